// Round 13
// baseline (88.396 us; speedup 1.0000x reference)
//
#include <hip/hip_runtime.h>
#include <math.h>
#include <stdint.h>

#define HIDDEN 4096
#define NEXP   64
#define TOKS   64                 // tokens per main block
#define KCH    64                 // k floats per staged chunk
#define NCHK   (HIDDEN / KCH)     // 64 chunks
#define X_FL   (TOKS * KCH)       // 4096 floats: X region (16 KB)
#define PAR_FL (X_FL + 2 * 2048)  // + Bhi 8KB + Blo 8KB = 8192 floats (32 KB)

typedef __bf16 bf16x8 __attribute__((ext_vector_type(8)));
typedef float  f32x4  __attribute__((ext_vector_type(4)));

union BfU { uint4 u; bf16x8 b; };

// fp32 -> (hi, lo) bf16 split; dropped lo*lo term ~2^-18 rel (R8-R12 verified).
static __device__ __forceinline__ void cvt_hilo(const float* x8, bf16x8& hi, bf16x8& lo) {
#pragma unroll
    for (int j = 0; j < 8; ++j) {
        const float x = x8[j];
        const __bf16 h = (__bf16)x;
        const float  r = x - (float)h;
        hi[j] = h;
        lo[j] = (__bf16)r;
    }
}

// async global->LDS, 16B/lane, wave-uniform dest base + lane*16
__device__ __forceinline__ void gload_lds16(const void* g, void* l) {
    __builtin_amdgcn_global_load_lds(
        (const __attribute__((address_space(1))) void*)g,
        (__attribute__((address_space(3))) void*)l, 16, 0, 0);
}

// ---- pre-kernel (R8-R12 verified): W fp32 -> B-fragment-ordered bf16 hi/lo.
// Fragment F = S*4 + e (S = k-step of 32): lane l supplies
// B[col 16e+(l&15)][k 32S+8(l>>4)+j] at ws[F*512 + l*8].
__global__ __launch_bounds__(512) void wconv_kernel(
    const float* __restrict__ W, ushort* __restrict__ wsHi, ushort* __restrict__ wsLo)
{
    const int gid = blockIdx.x * blockDim.x + threadIdx.x;   // 0..32767
    const int S = gid >> 8;
    const int e = (gid >> 6) & 3;
    const int l = gid & 63;
    const int row = 16 * e + (l & 15);
    const int k0  = 32 * S + 8 * (l >> 4);
    const float* src = W + (size_t)row * HIDDEN + k0;
    float x8[8];
    *(float4*)&x8[0] = *(const float4*)src;
    *(float4*)&x8[4] = *(const float4*)(src + 4);
    BfU hi, lo;
    cvt_hilo(x8, hi.b, lo.b);
    const size_t o = ((size_t)(S * 4 + e) * 64 + l) * 8;
    *(uint4*)(wsHi + o) = hi.u;
    *(uint4*)(wsLo + o) = lo.u;
}

// ---- main: bf16x3 MFMA router, R10 geometry + T3/T4 counted-vmcnt pipeline.
// KEY FIX vs R10-R12: __syncthreads() lowers to s_waitcnt vmcnt(0) + s_barrier
// (m97), draining the HBM queue every chunk (the ~30% duty loss). Here: RAW
// __builtin_amdgcn_s_barrier() + hand-counted vmcnt(2) -> chunk c+1's two
// staging loads stay IN FLIGHT across the barrier; queue never empties.
// Triple-buffered 32KB chunks (96KB LDS). 16 waves = tg(4) x eh(2) x kh(2):
// wave = 16 tok x 32 exp x one 32-k step per 64-k chunk; acc[2] = 8 VGPR.
// Per chunk per wave: 1 X gload_lds (1KB row-linear, source-granule XOR
// involution -> 8-lanes-per-slot = b128 bank floor) + 1 B-plane gload_lds
// (fragment-ordered ws, linear). sched_barrier(0) after s_barrier pins
// reads (race guard) and stage-writes (WAR guard) below the barrier.
__global__ __launch_bounds__(1024, 1) void router_mfma_kernel(
    const float* __restrict__ X,
    const ushort* __restrict__ wsHi, const ushort* __restrict__ wsLo,
    const float* __restrict__ Bv, float* __restrict__ out, int nTok)
{
    __shared__ float smem[3 * PAR_FL];   // 98304 B; epilogue aliases

    const int tid = threadIdx.x;
    const int wv  = tid >> 6;        // 0..15
    const int tg  = wv >> 2;         // token-group 0..3 (16 tokens each)
    const int eh  = (wv >> 1) & 1;   // expert-half 0..1 (32 experts each)
    const int kh  = wv & 1;          // k-step within chunk 0..1
    const int l   = tid & 63;
    const int g   = l >> 4;          // k-slot group 0..3
    const int cr  = l & 15;          // A row / B col within tile
    const int t0  = blockIdx.x * TOKS;

    // X staging (R12-verified formulas): wave wv stages rows 4wv..4wv+3;
    // lane l -> row 4wv+(l>>4), dest granule l&15 (linear dest = wv*1KB);
    // source granule (l&8)|((l&7)^(row&7)) (involution).
    const int srow = 4 * wv + (l >> 4);
    const int sgr  = (l & 8) | ((l & 7) ^ (srow & 7));
    const float* XgS = X + (size_t)(t0 + srow) * HIDDEN + sgr * 4;
    const int xdst  = wv * 256;                 // floats (uniform base)
    // B staging: chunk window = frags [8c, 8c+8) per plane; wave wv<8 stages
    // hi frag (wv), wv>=8 stages lo frag (wv-8). 1 instr each (lane-linear).
    const ushort* BS = (wv < 8 ? wsHi : wsLo) + (size_t)(wv & 7) * 512 + (size_t)l * 8;
    const int bdst = X_FL + (wv < 8 ? 0 : 2048) + (wv & 7) * 256;

    // A-frag read (R12-verified): row 16tg+cr, granule 8kh + ((2g+h)^(cr&7)).
    const int m8   = cr & 7;
    const int rowX = (16 * tg + cr) * KCH;
    const int rdA0 = rowX + 4 * (8 * kh + ((2 * g + 0) ^ m8));
    const int rdA1 = rowX + 4 * (8 * kh + ((2 * g + 1) ^ m8));
    // B read: frag idx within window = 4kh + 2eh + e
    const int bro = (4 * kh + 2 * eh) * 512 + l * 8;   // ushort offset

    f32x4 acc[2] = {{0.f,0.f,0.f,0.f},{0.f,0.f,0.f,0.f}};

    // prologue: stage chunk 0 -> buf0, chunk 1 -> buf1 (issue order = vmcnt order)
    gload_lds16(XgS, smem + xdst);
    gload_lds16(BS, smem + bdst);
    gload_lds16(XgS + KCH, smem + PAR_FL + xdst);
    gload_lds16(BS + 4096, smem + PAR_FL + bdst);

    int p = 0, q = 2;   // current buf, stage-dest buf ((p+2)%3)
#pragma unroll 1
    for (int c = 0; c < NCHK; ++c) {
        if (c + 2 < NCHK) asm volatile("s_waitcnt vmcnt(2)" ::: "memory");
        else              asm volatile("s_waitcnt vmcnt(0)" ::: "memory");
        __builtin_amdgcn_s_barrier();          // raw: does NOT drain vmcnt
        __builtin_amdgcn_sched_barrier(0);     // pin reads/stages below barrier
        if (c + 2 < NCHK) {
            float* pb = smem + q * PAR_FL;
            gload_lds16(XgS + (size_t)(c + 2) * KCH, pb + xdst);
            gload_lds16(BS + (size_t)(c + 2) * 4096, pb + bdst);
        }
        const float*  xb = smem + p * PAR_FL;
        const ushort* bh = (const ushort*)(xb + X_FL) + bro;
        const ushort* bl = bh + 4096;          // lo region (+2048 floats)
        float x8[8];
        *(float4*)&x8[0] = *(const float4*)(xb + rdA0);
        *(float4*)&x8[4] = *(const float4*)(xb + rdA1);
        bf16x8 xh, xo; cvt_hilo(x8, xh, xo);
#pragma unroll
        for (int e = 0; e < 2; ++e) {
            BfU ph, pl;
            ph.u = *(const uint4*)(bh + e * 512);
            pl.u = *(const uint4*)(bl + e * 512);
            acc[e] = __builtin_amdgcn_mfma_f32_16x16x32_bf16(xh, ph.b, acc[e], 0, 0, 0);
            acc[e] = __builtin_amdgcn_mfma_f32_16x16x32_bf16(xo, ph.b, acc[e], 0, 0, 0);
            acc[e] = __builtin_amdgcn_mfma_f32_16x16x32_bf16(xh, pl.b, acc[e], 0, 0, 0);
        }
        p = (p == 2) ? 0 : p + 1;
        q = (q == 2) ? 0 : q + 1;
    }

    __syncthreads();   // full drain; safe to alias LDS for epilogue

    // ---- epilogue: kh-combine via tiles[2][64][68] + transposed top-2
    float (*tiles)[64][68] = (float (*)[64][68])smem;   // 8704 floats
    float* tt = smem + 2 * 64 * 68;                     // 64*65 = 4160 floats

    // C/D layout (m89): row = 16tg + 4g + i, col = 16*(2eh+e) + cr
#pragma unroll
    for (int e = 0; e < 2; ++e) {
        const int e2 = 2 * eh + e;
#pragma unroll
        for (int i = 0; i < 4; ++i)
            tiles[kh][16 * tg + 4 * g + i][16 * e2 + cr] = acc[e][i];
    }
    __syncthreads();

    const size_t offSel = (size_t)nTok * 2;
    const size_t offLog = (size_t)nTok * 4;

    // combine 2 kh-partials + bias; store logits; build transposed tile
    {
        const int tok = tid >> 4;          // 0..63
        const int e4  = (tid & 15) * 4;
        const float4 s0 = *(const float4*)&tiles[0][tok][e4];
        const float4 s1 = *(const float4*)&tiles[1][tok][e4];
        const float4 bb = *(const float4*)(Bv + e4);
        const float4 r = make_float4(s0.x + s1.x + bb.x, s0.y + s1.y + bb.y,
                                     s0.z + s1.z + bb.z, s0.w + s1.w + bb.w);
        *(float4*)(out + offLog + (size_t)(t0 + tok) * NEXP + e4) = r;
        tt[(e4 + 0) * 65 + tok] = r.x;
        tt[(e4 + 1) * 65 + tok] = r.y;
        tt[(e4 + 2) * 65 + tok] = r.z;
        tt[(e4 + 3) * 65 + tok] = r.w;
    }
    __syncthreads();

    // top-2 + softmax (verified): strict > keeps lowest index on ties
    if (tid < TOKS) {
        const int t = tid;
        float m1 = -INFINITY, m2 = -INFINITY;
        int i1 = 0, i2 = 0;
#pragma unroll
        for (int e = 0; e < NEXP; ++e) {
            const float v = tt[e * 65 + t];
            if (v > m1)      { m2 = m1; i2 = i1; m1 = v; i1 = e; }
            else if (v > m2) { m2 = v; i2 = e; }
        }
        const float ex  = expf(m2 - m1);
        const float inv = 1.0f / (1.0f + ex);
        *(float2*)(out + (size_t)(t0 + t) * 2)          = make_float2(inv, ex * inv);
        *(float2*)(out + offSel + (size_t)(t0 + t) * 2) = make_float2((float)i1, (float)i2);
    }

    if (blockIdx.x == 0 && tid == 0)
        out[offLog + (size_t)nTok * NEXP] = 0.0f;   // aux_loss
}

extern "C" void kernel_launch(void* const* d_in, const int* in_sizes, int n_in,
                              void* d_out, int out_size, void* d_ws, size_t ws_size,
                              hipStream_t stream)
{
    const float* X  = (const float*)d_in[0];
    const float* W  = (const float*)d_in[1];
    const float* Bv = (const float*)d_in[2];
    float* out = (float*)d_out;
    const int nTok = in_sizes[0] / HIDDEN;    // 16384
    ushort* wsHi = (ushort*)d_ws;             // 512 KB
    ushort* wsLo = wsHi + (size_t)NEXP * HIDDEN;  // 512 KB

    wconv_kernel<<<256, 128, 0, stream>>>(W, wsHi, wsLo);
    router_mfma_kernel<<<nTok / TOKS, 1024, 0, stream>>>(X, wsHi, wsLo, Bv, out, nTok);
}

// Round 14
// 70.627 us; speedup vs baseline: 1.2516x; 1.2516x over previous
//
#include <hip/hip_runtime.h>
#include <math.h>
#include <stdint.h>

#define HIDDEN  4096
#define NEXP    64
#define TOKS    64                 // tokens per main block
#define KCH     128                // k floats per staged chunk
#define NCHK    (HIDDEN / KCH)     // 32 chunks
#define X_FL    (TOKS * KCH)       // 8192 floats: X region (32 KB)
#define PAR_FL  16384              // + Bhi 16KB + Blo 16KB = 64 KB per parity

typedef __bf16 bf16x8 __attribute__((ext_vector_type(8)));
typedef float  f32x4  __attribute__((ext_vector_type(4)));

union BfU { uint4 u; bf16x8 b; };

// fp32 -> (hi, lo) bf16 split; dropped lo*lo term ~2^-18 rel (R8-R13 verified).
static __device__ __forceinline__ void cvt_hilo(const float* x8, bf16x8& hi, bf16x8& lo) {
#pragma unroll
    for (int j = 0; j < 8; ++j) {
        const float x = x8[j];
        const __bf16 h = (__bf16)x;
        const float  r = x - (float)h;
        hi[j] = h;
        lo[j] = (__bf16)r;
    }
}

// async global->LDS, 16B/lane, wave-uniform dest base + lane*16
__device__ __forceinline__ void gload_lds16(const void* g, void* l) {
    __builtin_amdgcn_global_load_lds(
        (const __attribute__((address_space(1))) void*)g,
        (__attribute__((address_space(3))) void*)l, 16, 0, 0);
}

// ---- pre-kernel (R8-R13 verified; grid 256x128 = all CUs): W fp32 ->
// B-fragment-ordered bf16 hi/lo. Fragment F = S*4 + e (S = k-step of 32):
// lane l supplies B[col 16e+(l&15)][k 32S+8(l>>4)+j] at ws[F*512 + l*8].
__global__ __launch_bounds__(512) void wconv_kernel(
    const float* __restrict__ W, ushort* __restrict__ wsHi, ushort* __restrict__ wsLo)
{
    const int gid = blockIdx.x * blockDim.x + threadIdx.x;   // 0..32767
    const int S = gid >> 8;
    const int e = (gid >> 6) & 3;
    const int l = gid & 63;
    const int row = 16 * e + (l & 15);
    const int k0  = 32 * S + 8 * (l >> 4);
    const float* src = W + (size_t)row * HIDDEN + k0;
    float x8[8];
    *(float4*)&x8[0] = *(const float4*)src;
    *(float4*)&x8[4] = *(const float4*)(src + 4);
    BfU hi, lo;
    cvt_hilo(x8, hi.b, lo.b);
    const size_t o = ((size_t)(S * 4 + e) * 64 + l) * 8;
    *(uint4*)(wsHi + o) = hi.u;
    *(uint4*)(wsLo + o) = lo.u;
}

// ---- main: R10 geometry EXACTLY (best verified: 70.8us) with the sync
// structure replaced by a 2-barrier counted-vmcnt pipeline (T3/T4, m201):
//   iter c: vmcnt(4) [c's stages landed; c+1's 4 stay in flight]
//           s_barrier (B1, raw -- no drain)
//           compute c
//           s_barrier (B2: all reads of parity c&1 done -- execution only)
//           issue c+2 into parity c&1  [WAR-safe by B2]
// Queue never empties (>=4 loads/wave in flight) => HBM never idles across
// barriers. Lead time 2 chunks (~6400cyc) >> 900cyc HBM latency. NO
// sched_barrier (R13's 64x order-pinning was a confound, m141). KCH=128
// keeps 32 iterations. 16 waves = tg(4) x kh(4): wave = 16 tok x 64 exp x
// one 32-k step/chunk; 2 A ds_read_b128 + 8 B ds_reads + 12 MFMA.
__global__ __launch_bounds__(1024, 1) void router_mfma_kernel(
    const float* __restrict__ X,
    const ushort* __restrict__ wsHi, const ushort* __restrict__ wsLo,
    const float* __restrict__ Bv, float* __restrict__ out, int nTok)
{
    __shared__ float smem[2 * PAR_FL];   // 131072 B; epilogue aliases

    const int tid = threadIdx.x;
    const int wv  = tid >> 6;
    const int tg  = wv >> 2;        // token-group 0..3
    const int kh  = wv & 3;         // k-step within chunk 0..3
    const int l   = tid & 63;
    const int g   = l >> 4;         // k-slot group 0..3
    const int cr  = l & 15;         // A row / B col within tile
    const int t0  = blockIdx.x * TOKS;

    // X staging (R10-verified): 32 instrs, 2 per wave; instr q=2wv+r covers
    // rows 2q,2q+1 (512B each). Lane l: row = 2q+(l>>5), granule (l&31)^(row&7).
    const float* XgS[2];
    int xdst[2];
#pragma unroll
    for (int r = 0; r < 2; ++r) {
        const int q   = 2 * wv + r;
        const int row = 2 * q + (l >> 5);
        XgS[r]  = X + (size_t)(t0 + row) * HIDDEN + (((l & 31) ^ (row & 7)) << 2);
        xdst[r] = 2 * q * KCH;      // uniform base; HW adds lane*16B
    }
    // B staging (R10-verified): wave wv stages hi frag 16c+wv and lo frag
    // 16c+wv (1KB linear each)
    const ushort* BhS = wsHi + (size_t)wv * 512 + (size_t)l * 8;
    const ushort* BlS = wsLo + (size_t)wv * 512 + (size_t)l * 8;
    const int bhdst = X_FL + wv * 256;          // float offsets, uniform
    const int bldst = X_FL + 4096 + wv * 256;

    // A-frag read (R10-verified): row 16tg+cr; k-step kh; granule
    // 8kh + ((2g+h)^(cr&7)).
    const int m8   = cr & 7;
    const int rowX = (16 * tg + cr) * KCH;
    const int gA0  = (8 * kh + ((2 * g + 0) ^ m8)) << 2;
    const int gA1  = (8 * kh + ((2 * g + 1) ^ m8)) << 2;

    f32x4 acc[4] = {{0.f,0.f,0.f,0.f},{0.f,0.f,0.f,0.f},{0.f,0.f,0.f,0.f},{0.f,0.f,0.f,0.f}};

    // prologue: stage chunk 0 -> parity 0, chunk 1 -> parity 1
    // (issue order = vmcnt retire order: [c0 x4, c1 x4])
#pragma unroll
    for (int r = 0; r < 2; ++r) gload_lds16(XgS[r], smem + xdst[r]);
    gload_lds16(BhS, smem + bhdst);
    gload_lds16(BlS, smem + bldst);
#pragma unroll
    for (int r = 0; r < 2; ++r) gload_lds16(XgS[r] + KCH, smem + PAR_FL + xdst[r]);
    gload_lds16(BhS + 8192, smem + PAR_FL + bhdst);
    gload_lds16(BlS + 8192, smem + PAR_FL + bldst);

#pragma unroll 1
    for (int c = 0; c < NCHK; ++c) {
        if (c + 1 < NCHK) asm volatile("s_waitcnt vmcnt(4)" ::: "memory");
        else              asm volatile("s_waitcnt vmcnt(0)" ::: "memory");
        __builtin_amdgcn_s_barrier();          // B1: everyone's chunk-c landed
        const int p = c & 1;
        {
            const float*  xb = smem + p * PAR_FL;
            const ushort* bh = (const ushort*)(xb + X_FL) + (4 * kh) * 512 + l * 8;
            const ushort* bl = bh + 8192;      // Blo region (+16KB)
            float x8[8];
            *(float4*)&x8[0] = *(const float4*)(xb + rowX + gA0);
            *(float4*)&x8[4] = *(const float4*)(xb + rowX + gA1);
            bf16x8 xh, xo; cvt_hilo(x8, xh, xo);
#pragma unroll
            for (int e = 0; e < 4; ++e) {
                BfU ph, pl;
                ph.u = *(const uint4*)(bh + e * 512);
                pl.u = *(const uint4*)(bl + e * 512);
                acc[e] = __builtin_amdgcn_mfma_f32_16x16x32_bf16(xh, ph.b, acc[e], 0, 0, 0);
                acc[e] = __builtin_amdgcn_mfma_f32_16x16x32_bf16(xo, ph.b, acc[e], 0, 0, 0);
                acc[e] = __builtin_amdgcn_mfma_f32_16x16x32_bf16(xh, pl.b, acc[e], 0, 0, 0);
            }
        }
        __builtin_amdgcn_s_barrier();          // B2: all reads of parity p done
        if (c + 2 < NCHK) {                    // issue c+2 -> parity p (freed)
            float* pb = smem + p * PAR_FL;
            const int ko = (c + 2) * KCH;
            const size_t bo = (size_t)(c + 2) * 8192;
#pragma unroll
            for (int r = 0; r < 2; ++r) gload_lds16(XgS[r] + ko, pb + xdst[r]);
            gload_lds16(BhS + bo, pb + bhdst);
            gload_lds16(BlS + bo, pb + bldst);
        }
    }

    __syncthreads();   // full drain; safe to alias LDS for epilogue

    // ---- epilogue (R8-R10 verified), LDS aliased: tiles 69632B + tt 16640B
    float (*tiles)[64][68] = (float (*)[64][68])smem;
    float* tt = smem + 4 * 64 * 68;

    // C/D layout (m89): row = 16tg + 4g + i, col = 16e + cr
#pragma unroll
    for (int e = 0; e < 4; ++e)
#pragma unroll
        for (int i = 0; i < 4; ++i)
            tiles[kh][16 * tg + 4 * g + i][16 * e + cr] = acc[e][i];
    __syncthreads();

    const size_t offSel = (size_t)nTok * 2;
    const size_t offLog = (size_t)nTok * 4;

    // combine 4 K-split partials + bias; store logits; build transposed tile
    {
        const int tok = tid >> 4;          // 0..63
        const int e4  = (tid & 15) * 4;
        const float4 s0 = *(const float4*)&tiles[0][tok][e4];
        const float4 s1 = *(const float4*)&tiles[1][tok][e4];
        const float4 s2 = *(const float4*)&tiles[2][tok][e4];
        const float4 s3 = *(const float4*)&tiles[3][tok][e4];
        const float4 bb = *(const float4*)(Bv + e4);
        const float4 r = make_float4(s0.x + s1.x + s2.x + s3.x + bb.x,
                                     s0.y + s1.y + s2.y + s3.y + bb.y,
                                     s0.z + s1.z + s2.z + s3.z + bb.z,
                                     s0.w + s1.w + s2.w + s3.w + bb.w);
        *(float4*)(out + offLog + (size_t)(t0 + tok) * NEXP + e4) = r;
        tt[(e4 + 0) * 65 + tok] = r.x;
        tt[(e4 + 1) * 65 + tok] = r.y;
        tt[(e4 + 2) * 65 + tok] = r.z;
        tt[(e4 + 3) * 65 + tok] = r.w;
    }
    __syncthreads();

    // top-2 + softmax (verified): strict > keeps lowest index on ties
    if (tid < 64) {
        const int t = tid;
        float m1 = -INFINITY, m2 = -INFINITY;
        int i1 = 0, i2 = 0;
#pragma unroll
        for (int e = 0; e < NEXP; ++e) {
            const float v = tt[e * 65 + t];
            if (v > m1)      { m2 = m1; i2 = i1; m1 = v; i1 = e; }
            else if (v > m2) { m2 = v; i2 = e; }
        }
        const float ex  = expf(m2 - m1);
        const float inv = 1.0f / (1.0f + ex);
        *(float2*)(out + (size_t)(t0 + t) * 2)          = make_float2(inv, ex * inv);
        *(float2*)(out + offSel + (size_t)(t0 + t) * 2) = make_float2((float)i1, (float)i2);
    }

    if (blockIdx.x == 0 && tid == 0)
        out[offLog + (size_t)nTok * NEXP] = 0.0f;   // aux_loss
}

extern "C" void kernel_launch(void* const* d_in, const int* in_sizes, int n_in,
                              void* d_out, int out_size, void* d_ws, size_t ws_size,
                              hipStream_t stream)
{
    const float* X  = (const float*)d_in[0];
    const float* W  = (const float*)d_in[1];
    const float* Bv = (const float*)d_in[2];
    float* out = (float*)d_out;
    const int nTok = in_sizes[0] / HIDDEN;    // 16384
    ushort* wsHi = (ushort*)d_ws;             // 512 KB
    ushort* wsLo = wsHi + (size_t)NEXP * HIDDEN;  // 512 KB

    wconv_kernel<<<256, 128, 0, stream>>>(W, wsHi, wsLo);
    router_mfma_kernel<<<nTok / TOKS, 1024, 0, stream>>>(X, wsHi, wsLo, Bv, out, nTok);
}